// Round 8
// baseline (187.648 us; speedup 1.0000x reference)
//
#include <hip/hip_runtime.h>
#include <math.h>

// GCN 2-layer, N=100K, E=3.2M, feat 1->16->2, log_softmax.
//
// R5: sort tile in LDS, stream out coalesced (random-ORDER 8B writes amplify
//     ~2.8x at HBM; ascending-order fragmented runs ~2x only).
// R6: coop monolith destroyed TLP + ~90us coop overhead.
// R7: random global atomicAdd = memory-side RMW, ~32B HBM per 4B atomic. Never.
// R8: EPB 4096 + int4 loads fixed scatter.
// R9: agg grid-imbalance fix: NEUTRAL (not occupancy-bound).
// R10: reorder pass (tile->bucket regroup in pass A): +4us only — B/C savings
//     cancelled by A's extra write. Pass A (the regroup) is the dominant cost.
// R11 (this round): RADIX-STYLE pipeline — pay for dst-grouping ONCE.
//     hist -> rowscan -> bscan -> scatter2 (direct to final bucket-major
//     payload2, exact size E, no overflow path) -> deg -> B -> C.
//     Eliminates payload1 (25.6MB write + ~50MB fragmented re-read) and the
//     whole regroup kernel; adds dst re-read (12.8MB) + 2 tiny scans.
//     scatter2 computes each element's final global address at LDS-insert
//     time (adjp[bkt]+slot, stored in 16KB LDS) so write-out is 2 independent
//     ds_reads + ascending 8B store — no bucket(k) search.

static constexpr int BLOCK_S   = 512;    // hist/scatter2 threads
static constexpr int EPB       = 4096;   // edges per tile
static constexpr int VITERS    = EPB / (BLOCK_S * 4);  // 2 (int4 groups)
static constexpr int CHUNK     = 128;    // nodes per bucket (pow2)
static constexpr int LOG_CHUNK = 7;
static constexpr int BLOCK_A   = 512;    // agg threads
static constexpr int MAXNB     = 1024;   // max buckets (N <= 131072)
static constexpr int MAXBLK    = 1024;   // max tiles (E <= 4.19M)

// ======================= 512-thread pair-wise inclusive scan (2 barriers) ==
__device__ __forceinline__ unsigned int incl_scan512(unsigned int v,
                                                     unsigned int* wsum, int t) {
    unsigned int x = v;
#pragma unroll
    for (int off = 1; off < 64; off <<= 1) {
        unsigned int y = __shfl_up(x, off, 64);
        if ((t & 63) >= off) x += y;
    }
    if ((t & 63) == 63) wsum[t >> 6] = x;
    __syncthreads();
    if (t < 8) {
        unsigned int s = wsum[t];
#pragma unroll
        for (int off = 1; off < 8; off <<= 1) {
            unsigned int y = __shfl_up(s, off, 64);
            if (t >= off) s += y;
        }
        wsum[t] = s;
    }
    __syncthreads();
    return x + ((t >= 64) ? wsum[(t >> 6) - 1] : 0u);
}

// ======================= K1: per-tile histogram =======================
__global__ __launch_bounds__(BLOCK_S) void hist_kernel(
    const int* __restrict__ dst,
    unsigned int* __restrict__ histT,          // [nb][nblk]
    int E, int nb, int nblk) {
    __shared__ unsigned int hist[MAXNB];       // 4 KB
    const int blk  = blockIdx.x;
    const int base = blk * EPB;
    const int nE   = min(EPB, E - base);
    const int t    = threadIdx.x;

    hist[t]           = 0u;
    hist[t + BLOCK_S] = 0u;
    __syncthreads();

#pragma unroll
    for (int i = 0; i < VITERS; ++i) {
        const int k = 4 * t + i * 4 * BLOCK_S;
        if (k < nE) {
            const int4 d4 = *reinterpret_cast<const int4*>(&dst[base + k]);
            atomicAdd(&hist[(unsigned int)d4.x >> LOG_CHUNK], 1u);
            atomicAdd(&hist[(unsigned int)d4.y >> LOG_CHUNK], 1u);
            atomicAdd(&hist[(unsigned int)d4.z >> LOG_CHUNK], 1u);
            atomicAdd(&hist[(unsigned int)d4.w >> LOG_CHUNK], 1u);
        }
    }
    __syncthreads();
    if (2 * t < nb)     histT[(size_t)(2 * t) * nblk + blk]     = hist[2 * t];
    if (2 * t + 1 < nb) histT[(size_t)(2 * t + 1) * nblk + blk] = hist[2 * t + 1];
}

// ======================= K2a: per-bucket prefix over tiles =======================
__global__ __launch_bounds__(BLOCK_S) void rowscan_kernel(
    const unsigned int* __restrict__ histT,    // [nb][nblk]
    unsigned int* __restrict__ prefT,          // [nb][nblk] exclusive
    unsigned int* __restrict__ bucketTotal,    // [nb]
    int nblk) {
    __shared__ unsigned int wsum[8];
    const int b = blockIdx.x, t = threadIdx.x;
    const int e0 = 2 * t;
    unsigned int v0 = 0, v1 = 0;
    if (e0 < nblk) {                            // nblk even -> pair in-bounds
        const uint2 r = *reinterpret_cast<const uint2*>(&histT[(size_t)b * nblk + e0]);
        v0 = r.x; v1 = r.y;
    }
    const unsigned int incl = incl_scan512(v0 + v1, wsum, t);
    const unsigned int ex0  = incl - v0 - v1;
    const unsigned int ex1  = ex0 + v0;
    if (e0 < nblk)
        *reinterpret_cast<uint2*>(&prefT[(size_t)b * nblk + e0]) = make_uint2(ex0, ex1);
    if (t == BLOCK_S - 1) bucketTotal[b] = incl;
}

// ======================= K2b: scan over buckets =======================
__global__ __launch_bounds__(BLOCK_S) void bscan_kernel(
    const unsigned int* __restrict__ bucketTotal,
    unsigned int* __restrict__ bucketStart,    // [nb+1]
    int nb) {
    __shared__ unsigned int wsum[8];
    const int t = threadIdx.x;
    const unsigned int v0 = (2 * t < nb)     ? bucketTotal[2 * t]     : 0u;
    const unsigned int v1 = (2 * t + 1 < nb) ? bucketTotal[2 * t + 1] : 0u;
    const unsigned int incl = incl_scan512(v0 + v1, wsum, t);
    const unsigned int ex0  = incl - v0 - v1;
    const unsigned int ex1  = ex0 + v0;
    if (2 * t < nb)     bucketStart[2 * t]     = ex0;
    if (2 * t + 1 < nb) bucketStart[2 * t + 1] = ex1;
    if (t == BLOCK_S - 1) bucketStart[nb] = incl;   // == E
}

// ======================= K3: direct scatter to bucket-major payload2 =======================
__global__ __launch_bounds__(BLOCK_S) void scatter2_kernel(
    const int* __restrict__ src, const int* __restrict__ dst,
    const float* __restrict__ w,
    const unsigned int* __restrict__ prefT,
    const unsigned int* __restrict__ bucketStart,
    unsigned long long* __restrict__ payload2,  // [E]
    int E, int nb, int nblk) {
    __shared__ unsigned long long pbuf[EPB];    // 32 KB
    __shared__ unsigned int gaddrA[EPB];        // 16 KB final addr per slot
    __shared__ unsigned int hist[MAXNB];        // 4 KB (counts -> cursor)
    __shared__ int          adjp[MAXNB];        // 4 KB globalBase - localExcl
    __shared__ unsigned int wsum[8];
    const int blk  = blockIdx.x;
    const int base = blk * EPB;
    const int nE   = min(EPB, E - base);
    const int t    = threadIdx.x;

    hist[t]           = 0u;
    hist[t + BLOCK_S] = 0u;
    __syncthreads();

    int4 dc[VITERS];                            // static indexing -> VGPRs
#pragma unroll
    for (int i = 0; i < VITERS; ++i) {
        const int k = 4 * t + i * 4 * BLOCK_S;
        int4 d4 = make_int4(0, 0, 0, 0);
        if (k < nE) {
            d4 = *reinterpret_cast<const int4*>(&dst[base + k]);
            atomicAdd(&hist[(unsigned int)d4.x >> LOG_CHUNK], 1u);
            atomicAdd(&hist[(unsigned int)d4.y >> LOG_CHUNK], 1u);
            atomicAdd(&hist[(unsigned int)d4.z >> LOG_CHUNK], 1u);
            atomicAdd(&hist[(unsigned int)d4.w >> LOG_CHUNK], 1u);
        }
        dc[i] = d4;
    }
    __syncthreads();

    // pair-wise scan of counts -> tile-local exclusive offsets
    const unsigned int v0 = hist[2 * t], v1 = hist[2 * t + 1];
    const unsigned int inclp = incl_scan512(v0 + v1, wsum, t);
    const unsigned int ex0 = inclp - v0 - v1;
    const unsigned int ex1 = ex0 + v0;
    // adjp[r] = bucketStart[r] + prefT[r][blk] - localExcl[r]
    if (2 * t < nb) {
        const uint2 bs = *reinterpret_cast<const uint2*>(&bucketStart[2 * t]);
        adjp[2 * t] = (int)(bs.x + prefT[(size_t)(2 * t) * nblk + blk]) - (int)ex0;
        if (2 * t + 1 < nb)
            adjp[2 * t + 1] =
                (int)(bs.y + prefT[(size_t)(2 * t + 1) * nblk + blk]) - (int)ex1;
    }
    hist[2 * t]     = ex0;                      // -> cursor
    hist[2 * t + 1] = ex1;
    __syncthreads();

#pragma unroll
    for (int i = 0; i < VITERS; ++i) {
        const int k = 4 * t + i * 4 * BLOCK_S;
        if (k < nE) {
            const int4   d4 = dc[i];
            const int4   s4 = *reinterpret_cast<const int4*>(&src[base + k]);
            const float4 w4 = *reinterpret_cast<const float4*>(&w[base + k]);
#define SCAT_ONE(dd, ss, ww)                                                  \
            {                                                                 \
                const int bkt = (int)((unsigned int)(dd) >> LOG_CHUNK);       \
                const unsigned int slot = atomicAdd(&hist[bkt], 1u);          \
                pbuf[slot] =                                                  \
                    ((unsigned long long)__float_as_uint(ww) << 32) |         \
                    ((unsigned int)(ss) << LOG_CHUNK) |                       \
                    (unsigned int)((dd) & (CHUNK - 1));                       \
                gaddrA[slot] = (unsigned int)(adjp[bkt] + (int)slot);         \
            }
            SCAT_ONE(d4.x, s4.x, w4.x)
            SCAT_ONE(d4.y, s4.y, w4.y)
            SCAT_ONE(d4.z, s4.z, w4.z)
            SCAT_ONE(d4.w, s4.w, w4.w)
#undef SCAT_ONE
        }
    }
    __syncthreads();
    // write-out: ascending global addresses (runs contiguous, gaps between)
    for (int k = t; k < nE; k += BLOCK_S)
        payload2[gaddrA[k]] = pbuf[k];
}

// ======================= K4: deg -> dinv, xd (contiguous stream) =======================
__global__ __launch_bounds__(BLOCK_A) void deg2_kernel(
    const unsigned long long* __restrict__ payload2,
    const unsigned int* __restrict__ bucketStart,
    const float* __restrict__ x,
    float* __restrict__ dinv, float* __restrict__ xd,
    int N, int nb) {
    __shared__ float acc[CHUNK];
    const int b = blockIdx.x, t = threadIdx.x;
    if (t < CHUNK) acc[t] = 0.0f;
    __syncthreads();
    const unsigned int beg = bucketStart[b], end = bucketStart[b + 1];
    unsigned int i = beg + t;
    for (; i + 3u * BLOCK_A < end; i += 4u * BLOCK_A) {
        const unsigned long long p0 = payload2[i];
        const unsigned long long p1 = payload2[i + BLOCK_A];
        const unsigned long long p2 = payload2[i + 2u * BLOCK_A];
        const unsigned long long p3 = payload2[i + 3u * BLOCK_A];
        atomicAdd(&acc[(unsigned int)p0 & (CHUNK - 1)],
                  __uint_as_float((unsigned int)(p0 >> 32)));
        atomicAdd(&acc[(unsigned int)p1 & (CHUNK - 1)],
                  __uint_as_float((unsigned int)(p1 >> 32)));
        atomicAdd(&acc[(unsigned int)p2 & (CHUNK - 1)],
                  __uint_as_float((unsigned int)(p2 >> 32)));
        atomicAdd(&acc[(unsigned int)p3 & (CHUNK - 1)],
                  __uint_as_float((unsigned int)(p3 >> 32)));
    }
    for (; i < end; i += BLOCK_A) {
        const unsigned long long p = payload2[i];
        atomicAdd(&acc[(unsigned int)p & (CHUNK - 1)],
                  __uint_as_float((unsigned int)(p >> 32)));
    }
    __syncthreads();
    const int n = b * CHUNK + t;
    if (t < CHUNK && n < N) {
        const float d = acc[t] + 1.0f;           // self-loop fill 1.0
        const float r = (d > 0.0f) ? rsqrtf(d) : 0.0f;
        dinv[n] = r;
        xd[n]   = r * x[n];
    }
}

// ======================= K5/K6 shared body =======================
#define AGG2_BODY(GATHER_ARR)                                                 \
    const unsigned int beg = bucketStart[b], end = bucketStart[b + 1];        \
    unsigned int i = beg + t;                                                 \
    for (; i + 3u * BLOCK_A < end; i += 4u * BLOCK_A) {                       \
        const unsigned long long p0 = payload2[i];                            \
        const unsigned long long p1 = payload2[i + BLOCK_A];                  \
        const unsigned long long p2 = payload2[i + 2u * BLOCK_A];             \
        const unsigned long long p3 = payload2[i + 3u * BLOCK_A];             \
        const float f0 = GATHER_ARR[(int)(((unsigned int)p0) >> LOG_CHUNK)];  \
        const float f1 = GATHER_ARR[(int)(((unsigned int)p1) >> LOG_CHUNK)];  \
        const float f2 = GATHER_ARR[(int)(((unsigned int)p2) >> LOG_CHUNK)];  \
        const float f3 = GATHER_ARR[(int)(((unsigned int)p3) >> LOG_CHUNK)];  \
        atomicAdd(&acc[(unsigned int)p0 & (CHUNK - 1)],                       \
                  __uint_as_float((unsigned int)(p0 >> 32)) * f0);            \
        atomicAdd(&acc[(unsigned int)p1 & (CHUNK - 1)],                       \
                  __uint_as_float((unsigned int)(p1 >> 32)) * f1);            \
        atomicAdd(&acc[(unsigned int)p2 & (CHUNK - 1)],                       \
                  __uint_as_float((unsigned int)(p2 >> 32)) * f2);            \
        atomicAdd(&acc[(unsigned int)p3 & (CHUNK - 1)],                       \
                  __uint_as_float((unsigned int)(p3 >> 32)) * f3);            \
    }                                                                         \
    for (; i < end; i += BLOCK_A) {                                           \
        const unsigned long long p = payload2[i];                             \
        atomicAdd(&acc[(unsigned int)p & (CHUNK - 1)],                        \
                  __uint_as_float((unsigned int)(p >> 32)) *                  \
                      GATHER_ARR[(int)(((unsigned int)p) >> LOG_CHUNK)]);     \
    }

// ---- K5: s -> relu-MLP -> gd ----
__global__ __launch_bounds__(BLOCK_A) void s_gamma2_kernel(
    const unsigned long long* __restrict__ payload2,
    const unsigned int* __restrict__ bucketStart,
    const float* __restrict__ dinv,
    const float* __restrict__ xd,
    const float* __restrict__ W1,    // [16]
    const float* __restrict__ b1,    // [16]
    const float* __restrict__ W2,    // [16][2]
    float* __restrict__ gd, int N, int nb) {
    __shared__ float acc[CHUNK];
    const int b = blockIdx.x, t = threadIdx.x;
    if (t < CHUNK) acc[t] = 0.0f;
    __syncthreads();
    AGG2_BODY(xd)
    __syncthreads();
    const int n = b * CHUNK + t;
    if (t < CHUNK && n < N) {
        const float dv = dinv[n];
        const float sv = dv * (acc[t] + xd[n]);   // + self-loop dv*dv*x[n]
        float g = 0.0f;
#pragma unroll
        for (int f = 0; f < 16; ++f) {
            const float h = fmaxf(sv * W1[f] + b1[f], 0.0f);   // relu(layer1)
            g += h * (W2[2 * f + 1] - W2[2 * f + 0]);          // gamma = g1-g0
        }
        gd[n] = dv * g;                           // pre-scaled for layer 2
    }
}

// ---- K6: d -> log_softmax out ----
__global__ __launch_bounds__(BLOCK_A) void d_out2_kernel(
    const unsigned long long* __restrict__ payload2,
    const unsigned int* __restrict__ bucketStart,
    const float* __restrict__ dinv,
    const float* __restrict__ gd,
    const float* __restrict__ b2,    // [2]
    float* __restrict__ out, int N, int nb) {
    __shared__ float acc[CHUNK];
    const int b = blockIdx.x, t = threadIdx.x;
    if (t < CHUNK) acc[t] = 0.0f;
    __syncthreads();
    AGG2_BODY(gd)
    __syncthreads();
    const int n = b * CHUNK + t;
    if (t < CHUNK && n < N) {
        const float dv = dinv[n];
        const float d = dv * (acc[t] + gd[n]) + (b2[1] - b2[0]);
        // 2-class log_softmax from d = a1 - a0 (stable)
        const float lse = fmaxf(d, 0.0f) + log1pf(expf(-fabsf(d)));
        out[2 * n + 0] = -lse;
        out[2 * n + 1] = d - lse;
    }
}

// ======================= fallback: R3 global-atomic path =======================

static constexpr int BLOCK = 256;

__global__ void zero_kernel(float* __restrict__ a, float* __restrict__ b, int n2) {
    int i = blockIdx.x * blockDim.x + threadIdx.x;
    if (i < n2) { a[i] = 0.0f; b[i] = 0.0f; }
}
__global__ void deg_kernel(const int* __restrict__ dst, const float* __restrict__ w,
                           float* __restrict__ deg, int E) {
    int e = blockIdx.x * blockDim.x + threadIdx.x;
    if (e < E) atomicAdd(&deg[dst[e]], w[e]);
}
__global__ void dinv_kernel(float* __restrict__ deg, int N) {
    int n = blockIdx.x * blockDim.x + threadIdx.x;
    if (n < N) {
        float d = deg[n] + 1.0f;
        deg[n] = (d > 0.0f) ? rsqrtf(d) : 0.0f;
    }
}
__global__ void s_kernel(const int* __restrict__ src, const int* __restrict__ dst,
                         const float* __restrict__ w, const float* __restrict__ dinv,
                         const float* __restrict__ x, float* __restrict__ s, int E) {
    int e = blockIdx.x * blockDim.x + threadIdx.x;
    if (e < E) {
        int si = src[e], di = dst[e];
        atomicAdd(&s[di], dinv[si] * w[e] * dinv[di] * x[si]);
    }
}
__global__ void g_kernel(const float* __restrict__ s, const float* __restrict__ dinv,
                         const float* __restrict__ x, const float* __restrict__ W1,
                         const float* __restrict__ b1, const float* __restrict__ W2,
                         float2* __restrict__ g, int N) {
    int n = blockIdx.x * blockDim.x + threadIdx.x;
    if (n < N) {
        float dv = dinv[n];
        float sv = s[n] + dv * dv * x[n];
        float g0 = 0.0f, g1 = 0.0f;
#pragma unroll
        for (int f = 0; f < 16; ++f) {
            float h = fmaxf(sv * W1[f] + b1[f], 0.0f);
            g0 += h * W2[2 * f + 0];
            g1 += h * W2[2 * f + 1];
        }
        g[n] = make_float2(g0, g1);
    }
}
__global__ void agg2_kernel(const int* __restrict__ src, const int* __restrict__ dst,
                            const float* __restrict__ w, const float* __restrict__ dinv,
                            const float2* __restrict__ g, float* __restrict__ agg, int E) {
    int e = blockIdx.x * blockDim.x + threadIdx.x;
    if (e < E) {
        int si = src[e], di = dst[e];
        float norm = dinv[si] * w[e] * dinv[di];
        float2 gv = g[si];
        atomicAdd(&agg[2 * di + 0], norm * gv.x);
        atomicAdd(&agg[2 * di + 1], norm * gv.y);
    }
}
__global__ void out_kernel(float* __restrict__ out, const float* __restrict__ dinv,
                           const float2* __restrict__ g, const float* __restrict__ b2, int N) {
    int n = blockIdx.x * blockDim.x + threadIdx.x;
    if (n < N) {
        float dv2 = dinv[n] * dinv[n];
        float2 gv = g[n];
        float a0 = out[2 * n + 0] + dv2 * gv.x + b2[0];
        float a1 = out[2 * n + 1] + dv2 * gv.y + b2[1];
        float m = fmaxf(a0, a1);
        float lse = m + logf(expf(a0 - m) + expf(a1 - m));
        out[2 * n + 0] = a0 - lse;
        out[2 * n + 1] = a1 - lse;
    }
}

// ======================= launch =======================

extern "C" void kernel_launch(void* const* d_in, const int* in_sizes, int n_in,
                              void* d_out, int out_size, void* d_ws, size_t ws_size,
                              hipStream_t stream) {
    const float* x  = (const float*)d_in[0];
    const int*   ei = (const int*)d_in[1];     // [2, E] delivered as int32
    const float* w  = (const float*)d_in[2];
    const float* W1 = (const float*)d_in[3];
    const float* b1 = (const float*)d_in[4];
    const float* W2 = (const float*)d_in[5];
    const float* b2 = (const float*)d_in[6];
    float* out = (float*)d_out;

    const int N = in_sizes[0];
    const int E = in_sizes[2];
    const int* src = ei;
    const int* dst = ei + E;

    const int nb   = (N + CHUNK - 1) / CHUNK;   // 782
    const int nblk = (E + EPB - 1) / EPB;       // 782

    // ws layout (16B-aligned sections):
    // payload2 | histT | prefT | bucketTotal | bucketStart | dinv | xd | gd
    size_t off = 0;
    auto align16 = [](size_t v) { return (v + 15) & ~(size_t)15; };
    size_t payload2_off = off;  off = align16(off + (size_t)E * 8);
    size_t histT_off    = off;  off = align16(off + (size_t)nb * nblk * 4);
    size_t prefT_off    = off;  off = align16(off + (size_t)nb * nblk * 4);
    size_t btot_off     = off;  off = align16(off + (size_t)nb * 4);
    size_t bstart_off   = off;  off = align16(off + (size_t)(nb + 1) * 4);
    size_t dinv_off     = off;  off = align16(off + (size_t)N * 4);
    size_t xd_off       = off;  off = align16(off + (size_t)N * 4);
    size_t gd_off       = off;  off = align16(off + (size_t)N * 4);
    const size_t required = off;

    const bool fits = (nb <= MAXNB && nblk <= MAXBLK && (nblk & 1) == 0 &&
                       (E % 4) == 0 && ws_size >= required);

    if (fits) {
        char* wsb = (char*)d_ws;
        unsigned long long* payload2 = (unsigned long long*)(wsb + payload2_off);
        unsigned int* histT       = (unsigned int*)(wsb + histT_off);
        unsigned int* prefT       = (unsigned int*)(wsb + prefT_off);
        unsigned int* bucketTotal = (unsigned int*)(wsb + btot_off);
        unsigned int* bucketStart = (unsigned int*)(wsb + bstart_off);
        float* dinv = (float*)(wsb + dinv_off);
        float* xd   = (float*)(wsb + xd_off);
        float* gd   = (float*)(wsb + gd_off);

        hist_kernel    <<<nblk, BLOCK_S, 0, stream>>>(dst, histT, E, nb, nblk);
        rowscan_kernel <<<nb,   BLOCK_S, 0, stream>>>(histT, prefT, bucketTotal, nblk);
        bscan_kernel   <<<1,    BLOCK_S, 0, stream>>>(bucketTotal, bucketStart, nb);
        scatter2_kernel<<<nblk, BLOCK_S, 0, stream>>>(src, dst, w, prefT, bucketStart,
                                                      payload2, E, nb, nblk);
        deg2_kernel    <<<nb,   BLOCK_A, 0, stream>>>(payload2, bucketStart, x,
                                                      dinv, xd, N, nb);
        s_gamma2_kernel<<<nb,   BLOCK_A, 0, stream>>>(payload2, bucketStart, dinv, xd,
                                                      W1, b1, W2, gd, N, nb);
        d_out2_kernel  <<<nb,   BLOCK_A, 0, stream>>>(payload2, bucketStart, dinv, gd,
                                                      b2, out, N, nb);
    } else {
        // R3 fallback: global-atomic path (needs 4N floats of ws)
        float*  ws   = (float*)d_ws;
        float*  dinv = ws;
        float*  s    = ws + (size_t)N;
        float2* g    = (float2*)(ws + (size_t)2 * N);
        const int gridE  = (E + BLOCK - 1) / BLOCK;
        const int gridN  = (N + BLOCK - 1) / BLOCK;
        const int gridN2 = (2 * N + BLOCK - 1) / BLOCK;
        zero_kernel<<<gridN2, BLOCK, 0, stream>>>(ws, out, 2 * N);
        deg_kernel <<<gridE,  BLOCK, 0, stream>>>(dst, w, dinv, E);
        dinv_kernel<<<gridN,  BLOCK, 0, stream>>>(dinv, N);
        s_kernel   <<<gridE,  BLOCK, 0, stream>>>(src, dst, w, dinv, x, s, E);
        g_kernel   <<<gridN,  BLOCK, 0, stream>>>(s, dinv, x, W1, b1, W2, g, N);
        agg2_kernel<<<gridE,  BLOCK, 0, stream>>>(src, dst, w, dinv, g, out, E);
        out_kernel <<<gridN,  BLOCK, 0, stream>>>(out, dinv, g, b2, N);
    }
}